// Round 1
// baseline (3676.586 us; speedup 1.0000x reference)
//
#include <hip/hip_runtime.h>
#include <stdint.h>

#define HH 8
#define DDIM 512
#define KHEAD 64
#define FFD 64
#define LLEN 512
#define BBATCH 32
#define NTOK 16384  // L*B

typedef unsigned short u16;

__device__ __forceinline__ float bf2f(u16 u) {
    union { uint32_t i; float f; } v; v.i = ((uint32_t)u) << 16; return v.f;
}
__device__ __forceinline__ u16 f2bf(float f) {
    union { uint32_t i; float f; } v; v.f = f;
    return (u16)((v.i + 0x7FFFu + ((v.i >> 16) & 1u)) >> 16);
}
__device__ __forceinline__ float ldf(const float* p) { return *p; }
__device__ __forceinline__ float ldf(const u16* p) { return bf2f(*p); }

enum { M_PLAIN = 0, M_WQK = 1, M_SUBAUX = 2, M_RELU = 3, M_ADDAUX = 4 };

// Generic batched GEMM, both operands K-contiguous ("B^T form"):
//   C[m,n] = sum_k A[m,k] * B[n,k]
// Batch dims (h2, b2) with per-tensor strides. Output always bf16 (u16).
// Tiles: 64x64 C-tile, TK=16, 256 threads, 4x4 micro-tile per thread.
template<typename TA, typename TB, int MODE>
__global__ __launch_bounds__(256) void gemm_bt(
    const TA* __restrict__ A, const TB* __restrict__ B, u16* __restrict__ C,
    int M, int N, int Kd, int lda, int ldb, int ldc,
    long Ash, long Asb, long Bsh, long Bsb, long Csh, long Csb, int nB2,
    const float* __restrict__ bias,
    const void* __restrict__ auxp, long auxsh, long auxsb, int auxld)
{
    __shared__ float As[16][68];
    __shared__ float Bs[16][68];
    const int z = blockIdx.z;
    const int h2 = z / nB2, b2 = z % nB2;
    const TA* Ab = A + h2 * Ash + b2 * Asb;
    const TB* Bb = B + h2 * Bsh + b2 * Bsb;
    const long cof = h2 * Csh + b2 * Csb;
    const int m0 = blockIdx.x * 64, n0 = blockIdx.y * 64;
    const int t = threadIdx.x;
    const int tx = t & 15, ty = t >> 4;
    float acc[4][4] = {};
    for (int k0 = 0; k0 < Kd; k0 += 16) {
        #pragma unroll
        for (int i = 0; i < 4; ++i) {
            int mm = ty + i * 16;
            As[tx][mm] = ldf(&Ab[(long)(m0 + mm) * lda + (k0 + tx)]);
            Bs[tx][mm] = ldf(&Bb[(long)(n0 + mm) * ldb + (k0 + tx)]);
        }
        __syncthreads();
        #pragma unroll
        for (int kk = 0; kk < 16; ++kk) {
            const float4 a4 = *(const float4*)&As[kk][ty * 4];
            const float4 b4 = *(const float4*)&Bs[kk][tx * 4];
            float av[4] = {a4.x, a4.y, a4.z, a4.w};
            float bv[4] = {b4.x, b4.y, b4.z, b4.w};
            #pragma unroll
            for (int i = 0; i < 4; ++i)
                #pragma unroll
                for (int j = 0; j < 4; ++j)
                    acc[i][j] += av[i] * bv[j];
        }
        __syncthreads();
    }

    if (MODE == M_WQK) {
        // per-row L2 norm over the 64-col tile (tile == one head's K block),
        // then scatter to wq/wk layout [H][B][L][KHEAD] as bf16.
        float* red = &As[0][0];  // 1088 floats of scratch
        #pragma unroll
        for (int i = 0; i < 4; ++i) {
            float s = 0.f;
            #pragma unroll
            for (int j = 0; j < 4; ++j) s += acc[i][j] * acc[i][j];
            red[(ty * 4 + i) * 16 + tx] = s;
        }
        __syncthreads();
        if (t < 64) {
            float s = 0.f;
            #pragma unroll
            for (int x = 0; x < 16; ++x) s += red[t * 16 + x];
            red[1024 + t] = 1.0f / fmaxf(sqrtf(s), 1e-12f);
        }
        __syncthreads();
        const int h = n0 >> 6;
        #pragma unroll
        for (int i = 0; i < 4; ++i) {
            const int m = m0 + ty * 4 + i;          // m = l*B + b
            const int l = m >> 5, bq = m & 31;
            const float inv = red[1024 + ty * 4 + i];
            u16* cp = C + (((long)(h * BBATCH + bq) * LLEN + l) * KHEAD + tx * 4);
            #pragma unroll
            for (int j = 0; j < 4; ++j) cp[j] = f2bf(acc[i][j] * inv);
        }
    } else {
        #pragma unroll
        for (int i = 0; i < 4; ++i) {
            const int m = m0 + ty * 4 + i;
            #pragma unroll
            for (int j = 0; j < 4; ++j) {
                const int n = n0 + tx * 4 + j;
                float v = acc[i][j];
                if (MODE == M_SUBAUX) {
                    const float* q = (const float*)auxp;
                    v = q[auxsh * h2 + auxsb * b2 + (long)m * auxld + n] - v;
                } else if (MODE == M_RELU) {
                    if (bias) v += bias[h2 * N + n];
                    v = fmaxf(v, 0.0f);
                } else if (MODE == M_ADDAUX) {
                    v += bias[h2 * N + n];
                    const u16* ax = (const u16*)auxp;
                    v += bf2f(ax[auxsh * h2 + auxsb * b2 + (long)m * auxld + n]);
                }
                C[cof + (long)m * ldc + n] = f2bf(v);
            }
        }
    }
}

// Pass A: per (h,b): dot = wq @ wk^T (both L2-normalized, K=64), softmax over k,
// write P (bf16) and accumulate column sums over q into colsum (fp32).
// Block = (qt, b, h), 64 q-rows per block; thread (tx,ty): 4 rows x 32 ks (k = j*16+tx).
__global__ __launch_bounds__(256) void attn_pass_a(
    const u16* __restrict__ wq, const u16* __restrict__ wk,
    u16* __restrict__ P, float* __restrict__ colsum)
{
    __shared__ u16 wqs[64 * 72];
    __shared__ u16 wks[512 * 72];
    __shared__ float cs[512];
    const int qt = blockIdx.x, b = blockIdx.y, h = blockIdx.z;
    const int t = threadIdx.x;
    const long hb = h * BBATCH + b;
    const u16* wqp = wq + (hb * LLEN + qt * 64) * KHEAD;
    const u16* wkp = wk + hb * LLEN * KHEAD;
    for (int u = t; u < 512; u += 256) {
        int r = u >> 3, c0 = (u & 7) * 8;
        *(uint4*)&wqs[r * 72 + c0] = ((const uint4*)wqp)[u];
    }
    for (int u = t; u < 4096; u += 256) {
        int r = u >> 3, c0 = (u & 7) * 8;
        *(uint4*)&wks[r * 72 + c0] = ((const uint4*)wkp)[u];
    }
    cs[t] = 0.f; cs[t + 256] = 0.f;
    __syncthreads();

    const int tx = t & 15, ty = t >> 4;
    float acc[4][32];
    #pragma unroll
    for (int i = 0; i < 4; ++i)
        #pragma unroll
        for (int j = 0; j < 32; ++j) acc[i][j] = 0.f;

    for (int c = 0; c < 64; ++c) {
        float av[4];
        #pragma unroll
        for (int i = 0; i < 4; ++i) av[i] = bf2f(wqs[(ty * 4 + i) * 72 + c]);
        #pragma unroll
        for (int j = 0; j < 32; ++j) {
            const float kv = bf2f(wks[(j * 16 + tx) * 72 + c]);
            acc[0][j] += av[0] * kv;
            acc[1][j] += av[1] * kv;
            acc[2][j] += av[2] * kv;
            acc[3][j] += av[3] * kv;
        }
    }

    #pragma unroll
    for (int i = 0; i < 4; ++i) {
        float mx = acc[i][0];
        #pragma unroll
        for (int j = 1; j < 32; ++j) mx = fmaxf(mx, acc[i][j]);
        #pragma unroll
        for (int off = 8; off >= 1; off >>= 1) mx = fmaxf(mx, __shfl_xor(mx, off, 16));
        float sm = 0.f;
        #pragma unroll
        for (int j = 0; j < 32; ++j) { acc[i][j] = __expf(acc[i][j] - mx); sm += acc[i][j]; }
        #pragma unroll
        for (int off = 8; off >= 1; off >>= 1) sm += __shfl_xor(sm, off, 16);
        const float inv = 1.0f / sm;
        const int q = qt * 64 + ty * 4 + i;
        const long pbase = (hb * LLEN + q) * LLEN;
        #pragma unroll
        for (int j = 0; j < 32; ++j) {
            const float p = acc[i][j] * inv;
            acc[i][j] = p;
            P[pbase + j * 16 + tx] = f2bf(p);
        }
    }
    #pragma unroll
    for (int j = 0; j < 32; ++j) {
        const float s = acc[0][j] + acc[1][j] + acc[2][j] + acc[3][j];
        atomicAdd(&cs[j * 16 + tx], s);
    }
    __syncthreads();
    for (int k = t; k < 512; k += 256)
        atomicAdd(&colsum[hb * 512 + k], cs[k]);
}

// Scale wvT[h][b][e][k] by 1/(1e-9 + colsum[h][b][k]) in place (bf16, 8 elems/thread).
__global__ __launch_bounds__(256) void scale_wvt(u16* __restrict__ wvT,
                                                 const float* __restrict__ colsum)
{
    const long v = (long)blockIdx.x * 256 + threadIdx.x;  // uint4 index, 8.38M total
    const int k0 = (int)(v & 63) * 8;
    const long row = v >> 6;          // (h*B+b)*512 + e
    const long hb = row >> 9;
    const float* csp = colsum + hb * 512 + k0;
    uint4 x = ((uint4*)wvT)[v];
    u16* us = (u16*)&x;
    #pragma unroll
    for (int j = 0; j < 8; ++j) us[j] = f2bf(bf2f(us[j]) / (1e-9f + csp[j]));
    ((uint4*)wvT)[v] = x;
}

// Final: LayerNorm over D=512 of preLN[h][b*L+l][:] and scatter to
// d_out[l][b][h*D + d] (fp32). One wave per row, 8 elems per lane.
__global__ __launch_bounds__(256) void ln_out(
    const u16* __restrict__ x, const float* __restrict__ g,
    const float* __restrict__ bb, float* __restrict__ out)
{
    const int t = threadIdx.x;
    const int w = t >> 6, lane = t & 63;
    const long row = (long)blockIdx.x * 4 + w;   // h*16384 + b*512 + l
    const int h = (int)(row >> 14);
    const int t2 = (int)(row & 16383);
    const int b = t2 >> 9, l = t2 & 511;
    const u16* xp = x + row * DDIM;
    float v[8];
    float s = 0.f, sq = 0.f;
    #pragma unroll
    for (int j = 0; j < 8; ++j) {
        v[j] = bf2f(xp[j * 64 + lane]);
        s += v[j]; sq += v[j] * v[j];
    }
    #pragma unroll
    for (int off = 32; off >= 1; off >>= 1) {
        s += __shfl_xor(s, off);
        sq += __shfl_xor(sq, off);
    }
    const float mean = s * (1.0f / 512.0f);
    const float var = sq * (1.0f / 512.0f) - mean * mean;
    const float rs = rsqrtf(var + 1e-5f);
    const float* gp = g + h * DDIM;
    const float* bp = bb + h * DDIM;
    float* op = out + ((long)l * BBATCH + b) * (HH * DDIM) + h * DDIM;
    #pragma unroll
    for (int j = 0; j < 8; ++j) {
        const int d = j * 64 + lane;
        op[d] = (v[j] - mean) * rs * gp[d] + bp[d];
    }
}

extern "C" void kernel_launch(void* const* d_in, const int* in_sizes, int n_in,
                              void* d_out, int out_size, void* d_ws, size_t ws_size,
                              hipStream_t stream) {
    const float* query = (const float*)d_in[0];
    const float* key   = (const float*)d_in[1];
    const float* value = (const float*)d_in[2];
    const float* WK = (const float*)d_in[3];
    const float* WQ = (const float*)d_in[4];
    const float* WV = (const float*)d_in[5];
    const float* Wt = (const float*)d_in[6];
    const float* W1 = (const float*)d_in[7];
    const float* b1 = (const float*)d_in[8];
    const float* W2 = (const float*)d_in[9];
    const float* b2 = (const float*)d_in[10];
    const float* lng = (const float*)d_in[11];
    const float* lnb = (const float*)d_in[12];

    // Workspace layout (bytes). Peak ~319 MB.
    char* ws = (char*)d_ws;
    u16*  wq     = (u16*)(ws);                       // 16,777,216
    u16*  wk     = (u16*)(ws + 16777216);            // 16,777,216
    u16*  P      = (u16*)(ws + 33554432);            // 134,217,728  [H][B][L][L]
    u16*  o      = (u16*)(ws + 167772160);           // 134,217,728  [H][B*L][D]
    float* colsum = (float*)(ws + 301989888);        // 524,288      [H][B][L]
    u16*  hff    = (u16*)(ws + 302514176);           // 16,777,216   [H][B*L][FF]
    u16*  preLN  = P;                                // reuse (P dead after K5)
    // d_out doubles as scratch until the final LN kernel:
    u16*  qmo = (u16*)d_out;                         // 134,217,728  [H][B][L][D]
    u16*  wvT = (u16*)((char*)d_out + 134217728);    // 134,217,728  [H][B][D][L]

    if (ws_size < 319291392u) return;  // insufficient scratch — fail loudly

    hipMemsetAsync(colsum, 0, 524288, stream);

    const dim3 blk(256);

    // K1: wq/wk = l2norm(query/key @ WQ/WK^T), scatter [H,B,L,K] bf16
    gemm_bt<float, float, M_WQK><<<dim3(256, 8, 1), blk, 0, stream>>>(
        query, WQ, wq, NTOK, 512, 512, 512, 512, 0,
        0, 0, 0, 0, 0, 0, 1, nullptr, nullptr, 0, 0, 0);
    gemm_bt<float, float, M_WQK><<<dim3(256, 8, 1), blk, 0, stream>>>(
        key, WK, wk, NTOK, 512, 512, 512, 512, 0,
        0, 0, 0, 0, 0, 0, 1, nullptr, nullptr, 0, 0, 0);

    // K2: wvT[h,b,e,l] = sum_d WV[h,e,d]*value[l,b,d]   (batch h=8, b=32)
    gemm_bt<float, float, M_PLAIN><<<dim3(8, 8, 256), blk, 0, stream>>>(
        WV, value, wvT, 512, 512, 512, 512, BBATCH * DDIM, 512,
        (long)DDIM * DDIM, 0, 0, DDIM,
        (long)BBATCH * DDIM * LLEN, (long)DDIM * LLEN, 32, nullptr, nullptr, 0, 0, 0);

    // K3: softmax(QK^T) -> P, column sums -> colsum
    attn_pass_a<<<dim3(8, 32, 8), blk, 0, stream>>>(wq, wk, P, colsum);

    // K4: wvT *= 1/(1e-9 + colsum)  (folds the q-axis renorm into V)
    scale_wvt<<<dim3(32768), blk, 0, stream>>>(wvT, colsum);

    // K5: qmo[h,b,q,:] = query[q,b,:] - P @ wvT_scaled^T   (batch h,b)
    gemm_bt<u16, u16, M_SUBAUX><<<dim3(8, 8, 256), blk, 0, stream>>>(
        P, wvT, qmo, 512, 512, 512, 512, 512, 512,
        (long)BBATCH * LLEN * LLEN, (long)LLEN * LLEN,
        (long)BBATCH * DDIM * LLEN, (long)DDIM * LLEN,
        (long)BBATCH * LLEN * DDIM, (long)LLEN * DDIM, 32,
        nullptr, query, 0, DDIM, BBATCH * DDIM);

    // K6: o = relu(qmo @ Wt^T)   (batch h)
    gemm_bt<u16, float, M_RELU><<<dim3(256, 8, 8), blk, 0, stream>>>(
        qmo, Wt, o, NTOK, 512, 512, 512, 512, 512,
        (long)BBATCH * LLEN * DDIM, 0, (long)DDIM * DDIM, 0,
        (long)NTOK * DDIM, 0, 1, nullptr, nullptr, 0, 0, 0);

    // K7: hff = relu(o @ W1^T + b1)   (batch h)
    gemm_bt<u16, float, M_RELU><<<dim3(256, 1, 8), blk, 0, stream>>>(
        o, W1, hff, NTOK, 64, 512, 512, 512, 64,
        (long)NTOK * DDIM, 0, (long)FFD * DDIM, 0,
        (long)NTOK * FFD, 0, 1, b1, nullptr, 0, 0, 0);

    // K8: preLN = o + (hff @ W2^T + b2)   (batch h)
    gemm_bt<u16, float, M_ADDAUX><<<dim3(256, 8, 8), blk, 0, stream>>>(
        hff, W2, preLN, NTOK, 512, 64, 64, 64, 512,
        (long)NTOK * FFD, 0, (long)DDIM * FFD, 0,
        (long)NTOK * DDIM, 0, 1, b2, o, (long)NTOK * DDIM, 0, 512);

    // K9: LayerNorm + transpose-scatter to [L,B,H*D] fp32
    ln_out<<<dim3(32768), blk, 0, stream>>>(preLN, lng, lnb, (float*)d_out);
}

// Round 2
// 1082.034 us; speedup vs baseline: 3.3978x; 3.3978x over previous
//
#include <hip/hip_runtime.h>
#include <stdint.h>

#define HH 8
#define DDIM 512
#define KHEAD 64
#define FFD 64
#define LLEN 512
#define BBATCH 32
#define NTOK 16384  // L*B

typedef unsigned short u16;
typedef __attribute__((ext_vector_type(8))) __bf16 bf16x8;
typedef __attribute__((ext_vector_type(4))) float f32x4;

__device__ __forceinline__ float bf2f(u16 u) {
    union { uint32_t i; float f; } v; v.i = ((uint32_t)u) << 16; return v.f;
}
__device__ __forceinline__ u16 f2bf(float f) {
    union { uint32_t i; float f; } v; v.f = f;
    return (u16)((v.i + 0x7FFFu + ((v.i >> 16) & 1u)) >> 16);
}

__device__ __forceinline__ void gload16(const void* g, void* l) {
    __builtin_amdgcn_global_load_lds(
        (const __attribute__((address_space(1))) void*)g,
        (__attribute__((address_space(3))) void*)l, 16, 0, 0);
}

// fp32 -> bf16 (RNE), 4 elems/thread
__global__ __launch_bounds__(256) void f2bf4(const float* __restrict__ in,
                                             u16* __restrict__ out, int n4) {
    int i = blockIdx.x * 256 + threadIdx.x;
    if (i >= n4) return;
    float4 v = ((const float4*)in)[i];
    ushort4 o; o.x = f2bf(v.x); o.y = f2bf(v.y); o.z = f2bf(v.z); o.w = f2bf(v.w);
    ((ushort4*)out)[i] = o;
}

enum { M_PLAIN = 0, M_WQK = 1, M_SUBAUX = 2, M_RELU = 3, M_ADDAUX = 4 };

// MFMA batched GEMM, both operands K-contiguous ("B^T form"):
//   C[m,n] = sum_k A[m,k] * B[n,k]   (bf16 in, fp32 acc, bf16 out)
// BM x BN tile, BK=32, 256 threads (4 waves), 16x16x32 MFMA.
// BN=128: waves 2x2, 64x64 each (4x4 frags). BN=64: waves 4x1, 32x64 (2x4).
template<int BM, int BN, int MODE>
__global__ __launch_bounds__(256) void mgemm(
    const u16* __restrict__ A, const u16* __restrict__ B, u16* __restrict__ C,
    int Kd, int lda, int ldb, int ldc,
    long Ash, long Asb, long Bsh, long Bsb, long Csh, long Csb, int nB2,
    const float* __restrict__ bias, int biasN,
    const void* __restrict__ auxp, long auxsh, long auxsb, int auxld)
{
    constexpr int WC = (BN == 128) ? 2 : 1;
    constexpr int WR = 4 / WC;
    constexpr int WTM = BM / WR;
    constexpr int WTN = BN / WC;
    constexpr int MF = WTM / 16;
    constexpr int NF = WTN / 16;
    constexpr int NCA = (BM * 64) / 4096;   // global_load_lds calls for A tile
    constexpr int NCB = (BN * 64) / 4096;
    __shared__ u16 As[BM * 32];
    __shared__ u16 Bs[BN * 32];

    const int z = blockIdx.z;
    const int h2 = z / nB2, b2 = z % nB2;
    const u16* Ab = A + h2 * Ash + b2 * Asb;
    const u16* Bb = B + h2 * Bsh + b2 * Bsb;
    const int m0 = blockIdx.x * BM, n0 = blockIdx.y * BN;
    const int t = threadIdx.x;
    const int lane = t & 63;
    const int w = t >> 6;
    const int wr = w / WC, wc = w % WC;
    const int tb = t * 16;          // this thread's byte within a staged tile
    const int wb = (t & 192) * 16;  // wave-uniform LDS base byte

    f32x4 acc[MF][NF];
    #pragma unroll
    for (int m = 0; m < MF; ++m)
        #pragma unroll
        for (int n = 0; n < NF; ++n)
            #pragma unroll
            for (int i = 0; i < 4; ++i) acc[m][n][i] = 0.f;

    const int ko = (lane >> 4) * 16;  // byte offset of this lane-group's k slot

    for (int k0 = 0; k0 < Kd; k0 += 32) {
        #pragma unroll
        for (int c = 0; c < NCA; ++c) {
            const int byte = c * 4096 + tb;
            const int row = byte >> 6;
            gload16((const char*)(Ab + (long)(m0 + row) * lda + k0) + (byte & 63),
                    (char*)As + c * 4096 + wb);
        }
        #pragma unroll
        for (int c = 0; c < NCB; ++c) {
            const int byte = c * 4096 + tb;
            const int row = byte >> 6;
            gload16((const char*)(Bb + (long)(n0 + row) * ldb + k0) + (byte & 63),
                    (char*)Bs + c * 4096 + wb);
        }
        __syncthreads();  // drains vmcnt -> LDS tiles ready
        bf16x8 af[MF], bfr[NF];
        #pragma unroll
        for (int m = 0; m < MF; ++m)
            af[m] = *(const bf16x8*)((const char*)As + (wr * WTM + m * 16 + (lane & 15)) * 64 + ko);
        #pragma unroll
        for (int n = 0; n < NF; ++n)
            bfr[n] = *(const bf16x8*)((const char*)Bs + (wc * WTN + n * 16 + (lane & 15)) * 64 + ko);
        #pragma unroll
        for (int m = 0; m < MF; ++m)
            #pragma unroll
            for (int n = 0; n < NF; ++n)
                acc[m][n] = __builtin_amdgcn_mfma_f32_16x16x32_bf16(af[m], bfr[n], acc[m][n], 0, 0, 0);
        __syncthreads();  // everyone done reading before next stage
    }

    const int lr = (lane >> 4) * 4;
    const int lc = lane & 15;

    if constexpr (MODE == M_WQK) {
        // l2-normalize each row over this wave's 64-col slab (== one head),
        // scatter to [H][B][L][KHEAD] bf16.
        const int h = (n0 + wc * WTN) >> 6;
        #pragma unroll
        for (int m = 0; m < MF; ++m) {
            #pragma unroll
            for (int i = 0; i < 4; ++i) {
                float s = 0.f;
                #pragma unroll
                for (int n = 0; n < NF; ++n) { const float v = acc[m][n][i]; s += v * v; }
                s += __shfl_xor(s, 1); s += __shfl_xor(s, 2);
                s += __shfl_xor(s, 4); s += __shfl_xor(s, 8);
                const float inv = 1.0f / fmaxf(sqrtf(s), 1e-12f);
                const int r = m0 + wr * WTM + m * 16 + lr + i;  // token = l*B+b
                const int l = r >> 5, bq = r & 31;
                u16* dst = C + (((long)(h * BBATCH + bq) * LLEN + l) * KHEAD) + lc;
                #pragma unroll
                for (int n = 0; n < NF; ++n) dst[n * 16] = f2bf(acc[m][n][i] * inv);
            }
        }
    } else {
        const long cof = h2 * Csh + b2 * Csb;
        #pragma unroll
        for (int m = 0; m < MF; ++m) {
            #pragma unroll
            for (int i = 0; i < 4; ++i) {
                const int r = m0 + wr * WTM + m * 16 + lr + i;
                #pragma unroll
                for (int n = 0; n < NF; ++n) {
                    const int c = n0 + wc * WTN + n * 16 + lc;
                    float v = acc[m][n][i];
                    if (MODE == M_SUBAUX) {
                        const float* q = (const float*)auxp;
                        v = q[auxsh * h2 + auxsb * b2 + (long)r * auxld + c] - v;
                    } else if (MODE == M_RELU) {
                        if (bias) v += bias[h2 * biasN + c];
                        v = fmaxf(v, 0.0f);
                    } else if (MODE == M_ADDAUX) {
                        v += bias[h2 * biasN + c];
                        const u16* ax = (const u16*)auxp;
                        v += bf2f(ax[auxsh * h2 + auxsb * b2 + (long)r * auxld + c]);
                    }
                    C[cof + (long)r * ldc + c] = f2bf(v);
                }
            }
        }
    }
}

// softmax(QK^T) -> P (bf16), column sums over q -> colsum (fp32).
__global__ __launch_bounds__(256) void attn_pass_a(
    const u16* __restrict__ wq, const u16* __restrict__ wk,
    u16* __restrict__ P, float* __restrict__ colsum)
{
    __shared__ u16 wqs[64 * 72];
    __shared__ u16 wks[512 * 72];
    __shared__ float cs[512];
    const int qt = blockIdx.x, b = blockIdx.y, h = blockIdx.z;
    const int t = threadIdx.x;
    const long hb = h * BBATCH + b;
    const u16* wqp = wq + (hb * LLEN + qt * 64) * KHEAD;
    const u16* wkp = wk + hb * LLEN * KHEAD;
    for (int u = t; u < 512; u += 256) {
        int r = u >> 3, c0 = (u & 7) * 8;
        *(uint4*)&wqs[r * 72 + c0] = ((const uint4*)wqp)[u];
    }
    for (int u = t; u < 4096; u += 256) {
        int r = u >> 3, c0 = (u & 7) * 8;
        *(uint4*)&wks[r * 72 + c0] = ((const uint4*)wkp)[u];
    }
    cs[t] = 0.f; cs[t + 256] = 0.f;
    __syncthreads();

    const int tx = t & 15, ty = t >> 4;
    float acc[4][32];
    #pragma unroll
    for (int i = 0; i < 4; ++i)
        #pragma unroll
        for (int j = 0; j < 32; ++j) acc[i][j] = 0.f;

    for (int c = 0; c < 64; ++c) {
        float av[4];
        #pragma unroll
        for (int i = 0; i < 4; ++i) av[i] = bf2f(wqs[(ty * 4 + i) * 72 + c]);
        #pragma unroll
        for (int j = 0; j < 32; ++j) {
            const float kv = bf2f(wks[(j * 16 + tx) * 72 + c]);
            acc[0][j] += av[0] * kv;
            acc[1][j] += av[1] * kv;
            acc[2][j] += av[2] * kv;
            acc[3][j] += av[3] * kv;
        }
    }

    #pragma unroll
    for (int i = 0; i < 4; ++i) {
        float mx = acc[i][0];
        #pragma unroll
        for (int j = 1; j < 32; ++j) mx = fmaxf(mx, acc[i][j]);
        #pragma unroll
        for (int off = 8; off >= 1; off >>= 1) mx = fmaxf(mx, __shfl_xor(mx, off, 16));
        float sm = 0.f;
        #pragma unroll
        for (int j = 0; j < 32; ++j) { acc[i][j] = __expf(acc[i][j] - mx); sm += acc[i][j]; }
        #pragma unroll
        for (int off = 8; off >= 1; off >>= 1) sm += __shfl_xor(sm, off, 16);
        const float inv = 1.0f / sm;
        const int q = qt * 64 + ty * 4 + i;
        const long pbase = (hb * LLEN + q) * LLEN;
        #pragma unroll
        for (int j = 0; j < 32; ++j) {
            const float p = acc[i][j] * inv;
            acc[i][j] = p;
            P[pbase + j * 16 + tx] = f2bf(p);
        }
    }
    #pragma unroll
    for (int j = 0; j < 32; ++j) {
        const float s = acc[0][j] + acc[1][j] + acc[2][j] + acc[3][j];
        atomicAdd(&cs[j * 16 + tx], s);
    }
    __syncthreads();
    for (int k = t; k < 512; k += 256)
        atomicAdd(&colsum[hb * 512 + k], cs[k]);
}

// wvT[h][b][e][k] *= 1/(1e-9 + colsum[h][b][k])
__global__ __launch_bounds__(256) void scale_wvt(u16* __restrict__ wvT,
                                                 const float* __restrict__ colsum)
{
    const long v = (long)blockIdx.x * 256 + threadIdx.x;
    const int k0 = (int)(v & 63) * 8;
    const long row = v >> 6;
    const long hb = row >> 9;
    const float* csp = colsum + hb * 512 + k0;
    uint4 x = ((uint4*)wvT)[v];
    u16* us = (u16*)&x;
    #pragma unroll
    for (int j = 0; j < 8; ++j) us[j] = f2bf(bf2f(us[j]) / (1e-9f + csp[j]));
    ((uint4*)wvT)[v] = x;
}

// LayerNorm over D of preLN[h][b*L+l][:] -> d_out[l][b][h*D+d] fp32
__global__ __launch_bounds__(256) void ln_out(
    const u16* __restrict__ x, const float* __restrict__ g,
    const float* __restrict__ bb, float* __restrict__ out)
{
    const int t = threadIdx.x;
    const int w = t >> 6, lane = t & 63;
    const long row = (long)blockIdx.x * 4 + w;
    const int h = (int)(row >> 14);
    const int t2 = (int)(row & 16383);
    const int b = t2 >> 9, l = t2 & 511;
    const u16* xp = x + row * DDIM;
    float v[8];
    float s = 0.f, sq = 0.f;
    #pragma unroll
    for (int j = 0; j < 8; ++j) {
        v[j] = bf2f(xp[j * 64 + lane]);
        s += v[j]; sq += v[j] * v[j];
    }
    #pragma unroll
    for (int off = 32; off >= 1; off >>= 1) {
        s += __shfl_xor(s, off);
        sq += __shfl_xor(sq, off);
    }
    const float mean = s * (1.0f / 512.0f);
    const float var = sq * (1.0f / 512.0f) - mean * mean;
    const float rs = rsqrtf(var + 1e-5f);
    const float* gp = g + h * DDIM;
    const float* bp = bb + h * DDIM;
    float* op = out + ((long)l * BBATCH + b) * (HH * DDIM) + h * DDIM;
    #pragma unroll
    for (int j = 0; j < 8; ++j) {
        const int d = j * 64 + lane;
        op[d] = (v[j] - mean) * rs * gp[d] + bp[d];
    }
}

extern "C" void kernel_launch(void* const* d_in, const int* in_sizes, int n_in,
                              void* d_out, int out_size, void* d_ws, size_t ws_size,
                              hipStream_t stream) {
    const float* query = (const float*)d_in[0];
    const float* key   = (const float*)d_in[1];
    const float* value = (const float*)d_in[2];
    const float* WK = (const float*)d_in[3];
    const float* WQ = (const float*)d_in[4];
    const float* WV = (const float*)d_in[5];
    const float* Wt = (const float*)d_in[6];
    const float* W1 = (const float*)d_in[7];
    const float* b1 = (const float*)d_in[8];
    const float* W2 = (const float*)d_in[9];
    const float* b2 = (const float*)d_in[10];
    const float* lng = (const float*)d_in[11];
    const float* lnb = (const float*)d_in[12];

    // ---- workspace layout (bytes), peak 319,291,392 (same as round 1) ----
    char* ws = (char*)d_ws;
    // region [0, 134217728): pre-K3 bf16 copies; becomes P at K3; preLN at K8
    u16* qbf  = (u16*)(ws);
    u16* kbf  = (u16*)(ws + 16777216);
    u16* vbf  = (u16*)(ws + 33554432);
    u16* WQbf = (u16*)(ws + 50331648);
    u16* WKbf = (u16*)(ws + 50855936);
    u16* WVbf = (u16*)(ws + 51380224);
    u16* P    = (u16*)(ws);
    u16* preLN = P;
    u16* o    = (u16*)(ws + 134217728);
    float* colsum = (float*)(ws + 268435456);
    u16* hff  = (u16*)(ws + 268959744);
    // region [285736960, 319291392): wq/wk until K3; then Wt/W1/W2 bf16
    u16* wq   = (u16*)(ws + 285736960);
    u16* wk   = (u16*)(ws + 302514176);
    u16* Wtbf = (u16*)(ws + 285736960);
    u16* W1bf = (u16*)(ws + 289931264);
    u16* W2bf = (u16*)(ws + 290455552);
    // d_out doubles as scratch until K9 overwrites all of it:
    u16* qmo = (u16*)d_out;                        // [H][B][L][D]
    u16* wvT = (u16*)((char*)d_out + 134217728);   // [H][B][D][L]

    if (ws_size < 319291392u) return;

    hipMemsetAsync(colsum, 0, 524288, stream);
    const dim3 blk(256);

    // fp32 -> bf16 conversions (pre-K3 set)
    f2bf4<<<dim3(8192), blk, 0, stream>>>(query, qbf, 2097152);
    f2bf4<<<dim3(8192), blk, 0, stream>>>(key,   kbf, 2097152);
    f2bf4<<<dim3(8192), blk, 0, stream>>>(value, vbf, 2097152);
    f2bf4<<<dim3(256),  blk, 0, stream>>>(WQ, WQbf, 65536);
    f2bf4<<<dim3(256),  blk, 0, stream>>>(WK, WKbf, 65536);
    f2bf4<<<dim3(2048), blk, 0, stream>>>(WV, WVbf, 524288);

    // K1: wq/wk = l2norm(query/key @ WQ/WK^T) -> [H,B,L,K] bf16
    mgemm<128, 128, M_WQK><<<dim3(128, 4, 1), blk, 0, stream>>>(
        qbf, WQbf, wq, 512, 512, 512, 0,
        0, 0, 0, 0, 0, 0, 1, nullptr, 0, nullptr, 0, 0, 0);
    mgemm<128, 128, M_WQK><<<dim3(128, 4, 1), blk, 0, stream>>>(
        kbf, WKbf, wk, 512, 512, 512, 0,
        0, 0, 0, 0, 0, 0, 1, nullptr, 0, nullptr, 0, 0, 0);

    // K2: wvT[h,b,e,l] = sum_d WV[h,e,d]*value[l,b,d]
    mgemm<128, 128, M_PLAIN><<<dim3(4, 4, 256), blk, 0, stream>>>(
        WVbf, vbf, wvT, 512, 512, BBATCH * DDIM, 512,
        (long)DDIM * DDIM, 0, 0, DDIM,
        (long)BBATCH * DDIM * LLEN, (long)DDIM * LLEN, 32,
        nullptr, 0, nullptr, 0, 0, 0);

    // K3: softmax(QK^T) -> P, column sums -> colsum
    attn_pass_a<<<dim3(8, 32, 8), blk, 0, stream>>>(wq, wk, P, colsum);

    // weight conversions into the now-dead wq/wk region
    f2bf4<<<dim3(2048), blk, 0, stream>>>(Wt, Wtbf, 524288);
    f2bf4<<<dim3(256),  blk, 0, stream>>>(W1, W1bf, 65536);
    f2bf4<<<dim3(256),  blk, 0, stream>>>(W2, W2bf, 65536);

    // K4: fold the q-axis renorm into V
    scale_wvt<<<dim3(32768), blk, 0, stream>>>(wvT, colsum);

    // K5: qmo = query - P @ wvT^T
    mgemm<128, 128, M_SUBAUX><<<dim3(4, 4, 256), blk, 0, stream>>>(
        P, wvT, qmo, 512, 512, 512, 512,
        (long)BBATCH * LLEN * LLEN, (long)LLEN * LLEN,
        (long)BBATCH * DDIM * LLEN, (long)DDIM * LLEN,
        (long)BBATCH * LLEN * DDIM, (long)LLEN * DDIM, 32,
        nullptr, 0, query, 0, DDIM, BBATCH * DDIM);

    // K6: o = relu(qmo @ Wt^T)
    mgemm<128, 128, M_RELU><<<dim3(128, 4, 8), blk, 0, stream>>>(
        qmo, Wtbf, o, 512, 512, 512, 512,
        (long)NTOK * DDIM, 0, (long)DDIM * DDIM, 0,
        (long)NTOK * DDIM, 0, 1, nullptr, 512, nullptr, 0, 0, 0);

    // K7: hff = relu(o @ W1^T + b1)   (BN=64)
    mgemm<128, 64, M_RELU><<<dim3(128, 1, 8), blk, 0, stream>>>(
        o, W1bf, hff, 512, 512, 512, 64,
        (long)NTOK * DDIM, 0, (long)FFD * DDIM, 0,
        (long)NTOK * FFD, 0, 1, b1, 64, nullptr, 0, 0, 0);

    // K8: preLN = o + (hff @ W2^T + b2)   (Kd=64)
    mgemm<128, 128, M_ADDAUX><<<dim3(128, 4, 8), blk, 0, stream>>>(
        hff, W2bf, preLN, 64, 64, 64, 512,
        (long)NTOK * FFD, 0, (long)DDIM * FFD, 0,
        (long)NTOK * DDIM, 0, 1, b2, 512, o, (long)NTOK * DDIM, 0, 512);

    // K9: LayerNorm + transpose-scatter to [L,B,H*D] fp32
    ln_out<<<dim3(32768), blk, 0, stream>>>(preLN, lng, lnb, (float*)d_out);
}

// Round 3
// 812.339 us; speedup vs baseline: 4.5259x; 1.3320x over previous
//
#include <hip/hip_runtime.h>
#include <stdint.h>

#define HH 8
#define DDIM 512
#define KHEAD 64
#define FFD 64
#define LLEN 512
#define BBATCH 32
#define NTOK 16384  // L*B

typedef unsigned short u16;
typedef __attribute__((ext_vector_type(8))) __bf16 bf16x8;
typedef __attribute__((ext_vector_type(4))) float f32x4;

__device__ __forceinline__ float bf2f(u16 u) {
    union { uint32_t i; float f; } v; v.i = ((uint32_t)u) << 16; return v.f;
}
__device__ __forceinline__ u16 f2bf(float f) {
    union { uint32_t i; float f; } v; v.f = f;
    return (u16)((v.i + 0x7FFFu + ((v.i >> 16) & 1u)) >> 16);
}

__device__ __forceinline__ void gload16(const void* g, void* l) {
    __builtin_amdgcn_global_load_lds(
        (const __attribute__((address_space(1))) void*)g,
        (__attribute__((address_space(3))) void*)l, 16, 0, 0);
}

// fp32 -> bf16 (RNE), 4 elems/thread
__global__ __launch_bounds__(256) void f2bf4(const float* __restrict__ in,
                                             u16* __restrict__ out, int n4) {
    int i = blockIdx.x * 256 + threadIdx.x;
    if (i >= n4) return;
    float4 v = ((const float4*)in)[i];
    ushort4 o; o.x = f2bf(v.x); o.y = f2bf(v.y); o.z = f2bf(v.z); o.w = f2bf(v.w);
    ((ushort4*)out)[i] = o;
}

enum { M_PLAIN = 0, M_WQK = 1, M_SUBAUX = 2, M_RELU = 3, M_ADDAUX = 4, M_SCALECOL = 5 };

// MFMA batched GEMM, both operands K-contiguous ("B^T form"):
//   C[m,n] = sum_k A[m,k] * B[n,k]   (bf16 in, fp32 acc, bf16 out)
template<int BM, int BN, int MODE>
__global__ __launch_bounds__(256) void mgemm(
    const u16* __restrict__ A, const u16* __restrict__ B, u16* __restrict__ C,
    int Kd, int lda, int ldb, int ldc,
    long Ash, long Asb, long Bsh, long Bsb, long Csh, long Csb, int nB2,
    const float* __restrict__ bias, int biasN,
    const void* __restrict__ auxp, long auxsh, long auxsb, int auxld)
{
    constexpr int WC = (BN == 128) ? 2 : 1;
    constexpr int WR = 4 / WC;
    constexpr int WTM = BM / WR;
    constexpr int WTN = BN / WC;
    constexpr int MF = WTM / 16;
    constexpr int NF = WTN / 16;
    constexpr int NCA = (BM * 64) / 4096;
    constexpr int NCB = (BN * 64) / 4096;
    __shared__ u16 As[BM * 32];
    __shared__ u16 Bs[BN * 32];

    const int z = blockIdx.z;
    const int h2 = z / nB2, b2 = z % nB2;
    const u16* Ab = A + h2 * Ash + b2 * Asb;
    const u16* Bb = B + h2 * Bsh + b2 * Bsb;
    const int m0 = blockIdx.x * BM, n0 = blockIdx.y * BN;
    const int t = threadIdx.x;
    const int lane = t & 63;
    const int w = t >> 6;
    const int wr = w / WC, wc = w % WC;
    const int tb = t * 16;
    const int wb = (t & 192) * 16;

    f32x4 acc[MF][NF];
    #pragma unroll
    for (int m = 0; m < MF; ++m)
        #pragma unroll
        for (int n = 0; n < NF; ++n)
            #pragma unroll
            for (int i = 0; i < 4; ++i) acc[m][n][i] = 0.f;

    const int ko = (lane >> 4) * 16;

    for (int k0 = 0; k0 < Kd; k0 += 32) {
        #pragma unroll
        for (int c = 0; c < NCA; ++c) {
            const int byte = c * 4096 + tb;
            const int row = byte >> 6;
            gload16((const char*)(Ab + (long)(m0 + row) * lda + k0) + (byte & 63),
                    (char*)As + c * 4096 + wb);
        }
        #pragma unroll
        for (int c = 0; c < NCB; ++c) {
            const int byte = c * 4096 + tb;
            const int row = byte >> 6;
            gload16((const char*)(Bb + (long)(n0 + row) * ldb + k0) + (byte & 63),
                    (char*)Bs + c * 4096 + wb);
        }
        __syncthreads();
        bf16x8 af[MF], bfr[NF];
        #pragma unroll
        for (int m = 0; m < MF; ++m)
            af[m] = *(const bf16x8*)((const char*)As + (wr * WTM + m * 16 + (lane & 15)) * 64 + ko);
        #pragma unroll
        for (int n = 0; n < NF; ++n)
            bfr[n] = *(const bf16x8*)((const char*)Bs + (wc * WTN + n * 16 + (lane & 15)) * 64 + ko);
        #pragma unroll
        for (int m = 0; m < MF; ++m)
            #pragma unroll
            for (int n = 0; n < NF; ++n)
                acc[m][n] = __builtin_amdgcn_mfma_f32_16x16x32_bf16(af[m], bfr[n], acc[m][n], 0, 0, 0);
        __syncthreads();
    }

    const int lr = (lane >> 4) * 4;
    const int lc = lane & 15;

    if constexpr (MODE == M_WQK) {
        // l2-normalize each row over this wave's 64-col slab (== one head),
        // scatter to [H][B][L][KHEAD] bf16, XOR-swizzled within each 64-elem row:
        // element e stored at e ^ ((l&7)<<3)  (consumed by attn_mfma).
        const int h = (n0 + wc * WTN) >> 6;
        #pragma unroll
        for (int m = 0; m < MF; ++m) {
            #pragma unroll
            for (int i = 0; i < 4; ++i) {
                float s = 0.f;
                #pragma unroll
                for (int n = 0; n < NF; ++n) { const float v = acc[m][n][i]; s += v * v; }
                s += __shfl_xor(s, 1); s += __shfl_xor(s, 2);
                s += __shfl_xor(s, 4); s += __shfl_xor(s, 8);
                const float inv = 1.0f / fmaxf(sqrtf(s), 1e-12f);
                const int r = m0 + wr * WTM + m * 16 + lr + i;  // token = l*B+b
                const int l = r >> 5, bq = r & 31;
                const int sw = (l & 7) << 3;
                u16* rowp = C + (((long)(h * BBATCH + bq) * LLEN + l) * KHEAD);
                #pragma unroll
                for (int n = 0; n < NF; ++n)
                    rowp[(lc + n * 16) ^ sw] = f2bf(acc[m][n][i] * inv);
            }
        }
    } else {
        const long cof = h2 * Csh + b2 * Csb;
        #pragma unroll
        for (int m = 0; m < MF; ++m) {
            #pragma unroll
            for (int i = 0; i < 4; ++i) {
                const int r = m0 + wr * WTM + m * 16 + lr + i;
                #pragma unroll
                for (int n = 0; n < NF; ++n) {
                    const int c = n0 + wc * WTN + n * 16 + lc;
                    float v = acc[m][n][i];
                    if (MODE == M_SUBAUX) {
                        const float* q = (const float*)auxp;
                        v = q[auxsh * h2 + auxsb * b2 + (long)r * auxld + c] - v;
                    } else if (MODE == M_RELU) {
                        if (bias) v += bias[h2 * biasN + c];
                        v = fmaxf(v, 0.0f);
                    } else if (MODE == M_ADDAUX) {
                        v += bias[h2 * biasN + c];
                        const u16* ax = (const u16*)auxp;
                        v += bf2f(ax[auxsh * h2 + auxsb * b2 + (long)r * auxld + c]);
                    } else if (MODE == M_SCALECOL) {
                        const float* cs = (const float*)auxp + auxsh * h2 + auxsb * b2;
                        v *= 1.0f / (1e-9f + cs[c]);
                    }
                    C[cof + (long)r * ldc + c] = f2bf(v);
                }
            }
        }
    }
}

// MFMA QK^T + softmax: block = (qt, b, h) covers 64 q-rows x all 512 k.
// wq/wk are stored row-swizzled (e ^ ((l&7)<<3)); staging is a linear copy so
// LDS keeps the swizzle; fragment reads apply the same XOR -> ~conflict-free.
// Each wave: 64 rows x 128-col slab (MF=4, NF=8). Cross-wave softmax via LDS.
// Outputs: P bf16 [H][B][L][L], colsum[h][b][k] += sum_q P (global atomics).
__global__ __launch_bounds__(256) void attn_mfma(
    const u16* __restrict__ wq, const u16* __restrict__ wk,
    u16* __restrict__ P, float* __restrict__ colsum)
{
    __shared__ u16 qs[64 * 64];    // 8 KB
    __shared__ u16 ks[512 * 64];   // 64 KB
    __shared__ float smax[4][64];
    __shared__ float ssum[4][64];

    const int qt = blockIdx.x, b = blockIdx.y, h = blockIdx.z;
    const long hb = h * BBATCH + b;
    const int t = threadIdx.x;
    const int lane = t & 63, w = t >> 6;
    const int wb = (t & 192) * 16;

    const char* qg = (const char*)(wq + (hb * LLEN + qt * 64) * KHEAD);
    const char* kg = (const char*)(wk + hb * LLEN * KHEAD);
    #pragma unroll
    for (int c = 0; c < 2; ++c)
        gload16(qg + c * 4096 + t * 16, (char*)qs + c * 4096 + wb);
    #pragma unroll
    for (int c = 0; c < 16; ++c)
        gload16(kg + c * 4096 + t * 16, (char*)ks + c * 4096 + wb);
    __syncthreads();

    const int l15 = lane & 15;
    const int g = lane >> 4;
    const int swz = (lane & 7) << 4;

    f32x4 acc[4][8];
    #pragma unroll
    for (int m = 0; m < 4; ++m)
        #pragma unroll
        for (int n = 0; n < 8; ++n)
            #pragma unroll
            for (int i = 0; i < 4; ++i) acc[m][n][i] = 0.f;

    #pragma unroll
    for (int kk = 0; kk < 2; ++kk) {
        bf16x8 af[4];
        #pragma unroll
        for (int m = 0; m < 4; ++m) {
            const int row = m * 16 + l15;
            af[m] = *(const bf16x8*)((const char*)qs + row * 128 + ((g * 16 + kk * 64) ^ swz));
        }
        #pragma unroll
        for (int n = 0; n < 8; ++n) {
            const int row = (w * 8 + n) * 16 + l15;
            const bf16x8 bfr = *(const bf16x8*)((const char*)ks + row * 128 + ((g * 16 + kk * 64) ^ swz));
            #pragma unroll
            for (int m = 0; m < 4; ++m)
                acc[m][n] = __builtin_amdgcn_mfma_f32_16x16x32_bf16(af[m], bfr, acc[m][n], 0, 0, 0);
        }
    }

    // --- softmax over full 512-col rows (split across 4 waves) ---
    float rmax[4][4];
    #pragma unroll
    for (int m = 0; m < 4; ++m)
        #pragma unroll
        for (int i = 0; i < 4; ++i) {
            float mx = acc[m][0][i];
            #pragma unroll
            for (int n = 1; n < 8; ++n) mx = fmaxf(mx, acc[m][n][i]);
            mx = fmaxf(mx, __shfl_xor(mx, 1));
            mx = fmaxf(mx, __shfl_xor(mx, 2));
            mx = fmaxf(mx, __shfl_xor(mx, 4));
            mx = fmaxf(mx, __shfl_xor(mx, 8));
            if (l15 == 0) smax[w][m * 16 + g * 4 + i] = mx;
        }
    __syncthreads();
    #pragma unroll
    for (int m = 0; m < 4; ++m)
        #pragma unroll
        for (int i = 0; i < 4; ++i) {
            const int r = m * 16 + g * 4 + i;
            rmax[m][i] = fmaxf(fmaxf(smax[0][r], smax[1][r]),
                               fmaxf(smax[2][r], smax[3][r]));
        }
    float rinv[4][4];
    #pragma unroll
    for (int m = 0; m < 4; ++m)
        #pragma unroll
        for (int i = 0; i < 4; ++i) {
            float s = 0.f;
            #pragma unroll
            for (int n = 0; n < 8; ++n) {
                acc[m][n][i] = __expf(acc[m][n][i] - rmax[m][i]);
                s += acc[m][n][i];
            }
            s += __shfl_xor(s, 1); s += __shfl_xor(s, 2);
            s += __shfl_xor(s, 4); s += __shfl_xor(s, 8);
            if (l15 == 0) ssum[w][m * 16 + g * 4 + i] = s;
        }
    __syncthreads();
    #pragma unroll
    for (int m = 0; m < 4; ++m)
        #pragma unroll
        for (int i = 0; i < 4; ++i) {
            const int r = m * 16 + g * 4 + i;
            rinv[m][i] = 1.0f / (ssum[0][r] + ssum[1][r] + ssum[2][r] + ssum[3][r]);
        }

    // --- write P, accumulate column sums ---
    u16* Pb = P + (hb * LLEN + qt * 64) * LLEN + w * 128;
    float cs[8];
    #pragma unroll
    for (int n = 0; n < 8; ++n) cs[n] = 0.f;
    #pragma unroll
    for (int m = 0; m < 4; ++m)
        #pragma unroll
        for (int i = 0; i < 4; ++i) {
            const int r = m * 16 + g * 4 + i;
            u16* pr = Pb + (long)r * LLEN + l15;
            const float iv = rinv[m][i];
            #pragma unroll
            for (int n = 0; n < 8; ++n) {
                const float p = acc[m][n][i] * iv;
                pr[n * 16] = f2bf(p);
                cs[n] += p;
            }
        }
    #pragma unroll
    for (int n = 0; n < 8; ++n) {
        cs[n] += __shfl_xor(cs[n], 16);
        cs[n] += __shfl_xor(cs[n], 32);
    }
    if (lane < 16) {
        float* cb = colsum + hb * 512 + w * 128 + lane;
        #pragma unroll
        for (int n = 0; n < 8; ++n) atomicAdd(&cb[n * 16], cs[n]);
    }
}

// LayerNorm over D of preLN[h][b*L+l][:] -> d_out[l][b][h*D+d] fp32
__global__ __launch_bounds__(256) void ln_out(
    const u16* __restrict__ x, const float* __restrict__ g,
    const float* __restrict__ bb, float* __restrict__ out)
{
    const int t = threadIdx.x;
    const int w = t >> 6, lane = t & 63;
    const long row = (long)blockIdx.x * 4 + w;
    const int h = (int)(row >> 14);
    const int t2 = (int)(row & 16383);
    const int b = t2 >> 9, l = t2 & 511;
    const u16* xp = x + row * DDIM;
    float v[8];
    float s = 0.f, sq = 0.f;
    #pragma unroll
    for (int j = 0; j < 8; ++j) {
        v[j] = bf2f(xp[j * 64 + lane]);
        s += v[j]; sq += v[j] * v[j];
    }
    #pragma unroll
    for (int off = 32; off >= 1; off >>= 1) {
        s += __shfl_xor(s, off);
        sq += __shfl_xor(sq, off);
    }
    const float mean = s * (1.0f / 512.0f);
    const float var = sq * (1.0f / 512.0f) - mean * mean;
    const float rs = rsqrtf(var + 1e-5f);
    const float* gp = g + h * DDIM;
    const float* bp = bb + h * DDIM;
    float* op = out + ((long)l * BBATCH + b) * (HH * DDIM) + h * DDIM;
    #pragma unroll
    for (int j = 0; j < 8; ++j) {
        const int d = j * 64 + lane;
        op[d] = (v[j] - mean) * rs * gp[d] + bp[d];
    }
}

extern "C" void kernel_launch(void* const* d_in, const int* in_sizes, int n_in,
                              void* d_out, int out_size, void* d_ws, size_t ws_size,
                              hipStream_t stream) {
    const float* query = (const float*)d_in[0];
    const float* key   = (const float*)d_in[1];
    const float* value = (const float*)d_in[2];
    const float* WK = (const float*)d_in[3];
    const float* WQ = (const float*)d_in[4];
    const float* WV = (const float*)d_in[5];
    const float* Wt = (const float*)d_in[6];
    const float* W1 = (const float*)d_in[7];
    const float* b1 = (const float*)d_in[8];
    const float* W2 = (const float*)d_in[9];
    const float* b2 = (const float*)d_in[10];
    const float* lng = (const float*)d_in[11];
    const float* lnb = (const float*)d_in[12];

    // ---- workspace layout (bytes), peak 319,291,392 ----
    char* ws = (char*)d_ws;
    // [0, 128MB): qbf/kbf/WQbf/WKbf until K1; P from K3; preLN at K8
    u16* qbf  = (u16*)(ws);                    // 16 MB
    u16* kbf  = (u16*)(ws + 16777216);         // 16 MB
    u16* WQbf = (u16*)(ws + 33554432);         // 0.5 MB
    u16* WKbf = (u16*)(ws + 34078720);         // 0.5 MB
    u16* P    = (u16*)(ws);                    // 128 MB
    u16* preLN = P;
    // [128MB, 256MB): vbf/WVbf until K2; o from K6
    u16* vbf  = (u16*)(ws + 134217728);        // 16 MB
    u16* WVbf = (u16*)(ws + 150994944);        // 0.5 MB
    u16* o    = (u16*)(ws + 134217728);        // 128 MB
    float* colsum = (float*)(ws + 268435456);  // 0.5 MB
    u16* hff  = (u16*)(ws + 268959744);        // 16 MB
    // [285736960, 319291392): wq/wk until K3; then Wt/W1/W2 bf16
    u16* wq   = (u16*)(ws + 285736960);
    u16* wk   = (u16*)(ws + 302514176);
    u16* Wtbf = (u16*)(ws + 285736960);
    u16* W1bf = (u16*)(ws + 289931264);
    u16* W2bf = (u16*)(ws + 290455552);
    // d_out doubles as scratch until K9 overwrites all of it:
    u16* qmo = (u16*)d_out;                        // [H][B][L][D]
    u16* wvT = (u16*)((char*)d_out + 134217728);   // [H][B][D][L]

    if (ws_size < 319291392u) return;

    hipMemsetAsync(colsum, 0, 524288, stream);
    const dim3 blk(256);

    // fp32 -> bf16 conversions
    f2bf4<<<dim3(8192), blk, 0, stream>>>(query, qbf, 2097152);
    f2bf4<<<dim3(8192), blk, 0, stream>>>(key,   kbf, 2097152);
    f2bf4<<<dim3(8192), blk, 0, stream>>>(value, vbf, 2097152);
    f2bf4<<<dim3(256),  blk, 0, stream>>>(WQ, WQbf, 65536);
    f2bf4<<<dim3(256),  blk, 0, stream>>>(WK, WKbf, 65536);
    f2bf4<<<dim3(2048), blk, 0, stream>>>(WV, WVbf, 524288);

    // K1: wq/wk = l2norm(query/key @ WQ/WK^T) -> [H,B,L,K] bf16 (swizzled rows)
    mgemm<128, 128, M_WQK><<<dim3(128, 4, 1), blk, 0, stream>>>(
        qbf, WQbf, wq, 512, 512, 512, 0,
        0, 0, 0, 0, 0, 0, 1, nullptr, 0, nullptr, 0, 0, 0);
    mgemm<128, 128, M_WQK><<<dim3(128, 4, 1), blk, 0, stream>>>(
        kbf, WKbf, wk, 512, 512, 512, 0,
        0, 0, 0, 0, 0, 0, 1, nullptr, 0, nullptr, 0, 0, 0);

    // K3: MFMA softmax(QK^T) -> P, column sums -> colsum
    attn_mfma<<<dim3(8, 32, 8), blk, 0, stream>>>(wq, wk, P, colsum);

    // weight conversions into the now-dead wq/wk region
    f2bf4<<<dim3(2048), blk, 0, stream>>>(Wt, Wtbf, 524288);
    f2bf4<<<dim3(256),  blk, 0, stream>>>(W1, W1bf, 65536);
    f2bf4<<<dim3(256),  blk, 0, stream>>>(W2, W2bf, 65536);

    // K2: wvT[h,b,e,l] = (sum_d WV[h,e,d]*value[l,b,d]) / (1e-9+colsum[h,b,l])
    mgemm<128, 128, M_SCALECOL><<<dim3(4, 4, 256), blk, 0, stream>>>(
        WVbf, vbf, wvT, 512, 512, BBATCH * DDIM, 512,
        (long)DDIM * DDIM, 0, 0, DDIM,
        (long)BBATCH * DDIM * LLEN, (long)DDIM * LLEN, 32,
        nullptr, 0, colsum, (long)BBATCH * 512, 512, 0);

    // K5: qmo = query - P @ wvT^T
    mgemm<128, 128, M_SUBAUX><<<dim3(4, 4, 256), blk, 0, stream>>>(
        P, wvT, qmo, 512, 512, 512, 512,
        (long)BBATCH * LLEN * LLEN, (long)LLEN * LLEN,
        (long)BBATCH * DDIM * LLEN, (long)DDIM * LLEN,
        (long)BBATCH * LLEN * DDIM, (long)LLEN * DDIM, 32,
        nullptr, 0, query, 0, DDIM, BBATCH * DDIM);

    // K6: o = relu(qmo @ Wt^T)
    mgemm<128, 128, M_RELU><<<dim3(128, 4, 8), blk, 0, stream>>>(
        qmo, Wtbf, o, 512, 512, 512, 512,
        (long)NTOK * DDIM, 0, (long)DDIM * DDIM, 0,
        (long)NTOK * DDIM, 0, 1, nullptr, 512, nullptr, 0, 0, 0);

    // K7: hff = relu(o @ W1^T + b1)   (BN=64)
    mgemm<128, 64, M_RELU><<<dim3(128, 1, 8), blk, 0, stream>>>(
        o, W1bf, hff, 512, 512, 512, 64,
        (long)NTOK * DDIM, 0, (long)FFD * DDIM, 0,
        (long)NTOK * FFD, 0, 1, b1, 64, nullptr, 0, 0, 0);

    // K8: preLN = o + (hff @ W2^T + b2)   (Kd=64)
    mgemm<128, 128, M_ADDAUX><<<dim3(128, 4, 8), blk, 0, stream>>>(
        hff, W2bf, preLN, 64, 64, 64, 512,
        (long)NTOK * FFD, 0, (long)DDIM * FFD, 0,
        (long)NTOK * DDIM, 0, 1, b2, 512, o, (long)NTOK * DDIM, 0, 512);

    // K9: LayerNorm + transpose-scatter to [L,B,H*D] fp32
    ln_out<<<dim3(32768), blk, 0, stream>>>(preLN, lng, lnb, (float*)d_out);
}